// Round 6
// baseline (389.384 us; speedup 1.0000x reference)
//
#include <hip/hip_runtime.h>
#include <hip/hip_bf16.h>
#include <hip/hip_fp16.h>

#define IN_F 4096
#define OUT_F 16384
#define TOKENS 64

#define CHW 32                  // channels per wave
#define KSPLIT 8                // K split across waves
#define KCH (IN_F / KSPLIT)     // 512 k per wave
#define NITER (KCH / 32)        // 16 K-steps of 32
#define NRING 3                 // wave-private ring depth
#define TILE_B 4096             // 32 rows x 128 B per tile
#define BLOCK 256

typedef __attribute__((ext_vector_type(8))) short bf16x8;
typedef __attribute__((ext_vector_type(8))) unsigned short u16x8;
typedef __attribute__((ext_vector_type(4))) unsigned short u16x4;
typedef __attribute__((ext_vector_type(4))) float f32x4;
typedef __attribute__((ext_vector_type(4))) int i32x4;

enum { F_BF16 = 0, F_FP16 = 1, F_FP32 = 2 };

__device__ __forceinline__ float dec_bf16(unsigned short h) {
    return __uint_as_float(((unsigned)h) << 16);
}
__device__ __forceinline__ float dec_fp16(unsigned short h) {
    __half_raw hr; hr.x = h;
    return __half2float(__half(hr));
}
__device__ __forceinline__ unsigned short enc_bf16_rne(float f) {
    unsigned u = __float_as_uint(f);
    u += 0x7FFFu + ((u >> 16) & 1u);
    return (unsigned short)(u >> 16);
}

// Wave-uniform format detection (verified passing rounds 2-5 — keep verbatim).
__device__ __forceinline__ int detect_fmt16(const void* p, int lane, float lo, float hi) {
    unsigned short h = ((const unsigned short*)p)[lane];
    float vb = fabsf(dec_bf16(h));
    float vh = fabsf(dec_fp16(h));
    int cb = __popcll(__ballot(vb > lo && vb < hi));
    int ch = __popcll(__ballot(vh > lo && vh < hi));
    return (cb >= 56) ? F_BF16 : (ch >= 56) ? F_FP16 : F_FP32;
}
__device__ __forceinline__ int detect_wint(const int* w, int lane) {
    int v = w[lane];
    int ci = __popcll(__ballot(v >= -127 && v <= 127));
    return (ci >= 56) ? 1 : 0;
}

// ---------------- pre-kernel: x -> bf16 into workspace (verified) ------------
__global__ __launch_bounds__(256) void prep_x(const void* __restrict__ xv,
                                              unsigned short* __restrict__ xbf) {
    const int tid  = blockIdx.x * 256 + threadIdx.x;
    const int lane = threadIdx.x & 63;
    const int xf = detect_fmt16(xv, lane, 9.7e-4f, 64.0f);

    if (xf == F_BF16) {
        u16x8 a = ((const u16x8*)xv)[tid * 2];
        u16x8 b = ((const u16x8*)xv)[tid * 2 + 1];
        ((u16x8*)xbf)[tid * 2]     = a;
        ((u16x8*)xbf)[tid * 2 + 1] = b;
    } else if (xf == F_FP32) {
        u16x8 o[2];
        #pragma unroll
        for (int half = 0; half < 2; ++half) {
            f32x4 v0 = ((const f32x4*)xv)[tid * 4 + half * 2];
            f32x4 v1 = ((const f32x4*)xv)[tid * 4 + half * 2 + 1];
            #pragma unroll
            for (int j = 0; j < 4; ++j) {
                o[half][j]     = enc_bf16_rne(v0[j]);
                o[half][j + 4] = enc_bf16_rne(v1[j]);
            }
        }
        ((u16x8*)xbf)[tid * 2]     = o[0];
        ((u16x8*)xbf)[tid * 2 + 1] = o[1];
    } else { // F_FP16
        #pragma unroll
        for (int half = 0; half < 2; ++half) {
            u16x8 v = ((const u16x8*)xv)[tid * 2 + half];
            u16x8 o;
            #pragma unroll
            for (int j = 0; j < 8; ++j) o[j] = enc_bf16_rne(dec_fp16(v[j]));
            ((u16x8*)xbf)[tid * 2 + half] = o;
        }
    }
}

// ---------------- main: barrier-free wave-private ring staging ---------------
template <int WINT>
__device__ __forceinline__ void wave_kloop(
    const int* __restrict__ w, const unsigned short* __restrict__ xbf,
    char* __restrict__ myring, int wn0, int koff, int lane, int ln, int kq,
    f32x4 acc[8]) {

    const int rl = lane >> 3;           // row-within-8 this lane stages
    const int cc = (lane & 7) ^ rl;     // XOR-swizzled 16B chunk it fetches

    auto stage = [&](int t, int slot) {
        #pragma unroll
        for (int j = 0; j < 4; ++j) {
            const int r = j * 8 + rl;
            const int* g = w + (size_t)(wn0 + r) * IN_F + koff + t * 32 + cc * 4;
            __builtin_amdgcn_global_load_lds(
                (const __attribute__((address_space(1))) unsigned int*)g,
                (__attribute__((address_space(3))) unsigned int*)
                    (myring + slot * TILE_B + j * 1024 + lane * 16),
                16, 0, 0);
        }
    };

    const short* xs = (const short*)xbf;
    const size_t xr0 = (size_t)(ln     ) * IN_F;
    const size_t xr1 = (size_t)(ln + 16) * IN_F;
    const size_t xr2 = (size_t)(ln + 32) * IN_F;
    const size_t xr3 = (size_t)(ln + 48) * IN_F;

    // prologue: A(0) then S(0), S(1)  — issue order matters for vmcnt math
    int kk = koff + kq * 8;
    bf16x8 ca0 = *(const bf16x8*)(xs + xr0 + kk);
    bf16x8 ca1 = *(const bf16x8*)(xs + xr1 + kk);
    bf16x8 ca2 = *(const bf16x8*)(xs + xr2 + kk);
    bf16x8 ca3 = *(const bf16x8*)(xs + xr3 + kk);
    stage(0, 0);
    stage(1, 1);

    int sl = 0;
    for (int t = 0; t < NITER; ++t) {
        // issue A(t+1) then S(t+2)  (wrapped indices keep counts static)
        kk = koff + ((t + 1) & (NITER - 1)) * 32 + kq * 8;
        bf16x8 na0 = *(const bf16x8*)(xs + xr0 + kk);
        bf16x8 na1 = *(const bf16x8*)(xs + xr1 + kk);
        bf16x8 na2 = *(const bf16x8*)(xs + xr2 + kk);
        bf16x8 na3 = *(const bf16x8*)(xs + xr3 + kk);
        int s2 = sl + 2; if (s2 >= NRING) s2 -= NRING;
        stage((t + 2) & (NITER - 1), s2);

        // allow {A(t+1), S(t+1), S(t+2)} = 12 outstanding; S(t), A(t) must be done.
        // memory clobber pins VMEM issue order across this boundary.
        asm volatile("s_waitcnt vmcnt(12)" ::: "memory");

        const char* base = myring + sl * TILE_B;
        #pragma unroll
        for (int g = 0; g < 2; ++g) {
            const char* brow = base + (g * 16 + ln) * 128;
            i32x4 b0 = *(const i32x4*)(brow + (((kq * 2    ) ^ (ln & 7)) * 16));
            i32x4 b1 = *(const i32x4*)(brow + (((kq * 2 + 1) ^ (ln & 7)) * 16));
            bf16x8 bf;
            #pragma unroll
            for (int j = 0; j < 4; ++j) {
                unsigned f0 = WINT ? __float_as_uint((float)b0[j]) : (unsigned)b0[j];
                unsigned f1 = WINT ? __float_as_uint((float)b1[j]) : (unsigned)b1[j];
                bf[j]     = (short)(f0 >> 16);   // int8-valued -> bf16 exact
                bf[j + 4] = (short)(f1 >> 16);
            }
            acc[g*4+0] = __builtin_amdgcn_mfma_f32_16x16x32_bf16(ca0, bf, acc[g*4+0], 0, 0, 0);
            acc[g*4+1] = __builtin_amdgcn_mfma_f32_16x16x32_bf16(ca1, bf, acc[g*4+1], 0, 0, 0);
            acc[g*4+2] = __builtin_amdgcn_mfma_f32_16x16x32_bf16(ca2, bf, acc[g*4+2], 0, 0, 0);
            acc[g*4+3] = __builtin_amdgcn_mfma_f32_16x16x32_bf16(ca3, bf, acc[g*4+3], 0, 0, 0);
        }

        ca0 = na0; ca1 = na1; ca2 = na2; ca3 = na3;
        ++sl; if (sl >= NRING) sl = 0;
    }
}

__global__ __launch_bounds__(BLOCK) void w8a16_main(
    const int* __restrict__ w, const unsigned short* __restrict__ xbf,
    float* __restrict__ pws) {

    __shared__ alignas(16) char ring[4][NRING][TILE_B];   // 48 KB, wave-private slabs

    const int tid  = threadIdx.x;
    const int wv   = tid >> 6;
    const int lane = tid & 63;
    const int ln   = lane & 15;
    const int kq   = lane >> 4;

    const int gw   = blockIdx.x * 4 + wv;       // global wave id
    const int wn0  = (gw >> 3) * CHW;           // 32-channel group
    const int ks   = gw & 7;                    // K-split index
    const int koff = ks * KCH;

    const int wi = detect_wint(w, lane);

    f32x4 acc[8] = {};
    char* myring = &ring[wv][0][0];

    if (wi) wave_kloop<1>(w, xbf, myring, wn0, koff, lane, ln, kq, acc);
    else    wave_kloop<0>(w, xbf, myring, wn0, koff, lane, ln, kq, acc);

    // f32 partials: pws[ks][m][n]; D layout (m89): col=ln, row m = 16*tt + kq*4 + r
    float* pp = pws + (size_t)ks * TOKENS * OUT_F;
    #pragma unroll
    for (int g = 0; g < 2; ++g) {
        const int n = wn0 + g * 16 + ln;
        #pragma unroll
        for (int tt = 0; tt < 4; ++tt)
            #pragma unroll
            for (int r = 0; r < 4; ++r)
                pp[(size_t)(16 * tt + kq * 4 + r) * OUT_F + n] = acc[g * 4 + tt][r];
    }
}

// ---------------- reduce: 8-way K combine + scale/bias + format I/O ----------
__global__ __launch_bounds__(256) void reduce_k(
    const float* __restrict__ pws, const void* __restrict__ xv,
    const void* __restrict__ sv, const void* __restrict__ bv,
    void* __restrict__ yv) {

    const int t    = blockIdx.x * 256 + threadIdx.x;  // 262144 threads x 4 outputs
    const int lane = threadIdx.x & 63;
    const int xf = detect_fmt16(xv, lane, 9.7e-4f, 64.0f);
    const int sf = detect_fmt16(sv, lane, 1.0e-4f, 0.25f);

    const int base = t * 4;
    const int m    = base >> 14;
    const int n    = base & 16383;

    f32x4 s = {0.f, 0.f, 0.f, 0.f};
    #pragma unroll
    for (int ks = 0; ks < KSPLIT; ++ks) {
        f32x4 p = *(const f32x4*)(pws + (size_t)ks * TOKENS * OUT_F + (size_t)m * OUT_F + n);
        #pragma unroll
        for (int j = 0; j < 4; ++j) s[j] += p[j];
    }

    float sc[4], bi[4];
    if (sf == F_FP32) {
        f32x4 s4 = *(const f32x4*)((const float*)sv + n);
        f32x4 b4 = *(const f32x4*)((const float*)bv + n);
        #pragma unroll
        for (int j = 0; j < 4; ++j) { sc[j] = s4[j]; bi[j] = b4[j]; }
    } else if (sf == F_BF16) {
        u16x4 s4 = *(const u16x4*)((const unsigned short*)sv + n);
        u16x4 b4 = *(const u16x4*)((const unsigned short*)bv + n);
        #pragma unroll
        for (int j = 0; j < 4; ++j) { sc[j] = dec_bf16(s4[j]); bi[j] = dec_bf16(b4[j]); }
    } else {
        u16x4 s4 = *(const u16x4*)((const unsigned short*)sv + n);
        u16x4 b4 = *(const u16x4*)((const unsigned short*)bv + n);
        #pragma unroll
        for (int j = 0; j < 4; ++j) { sc[j] = dec_fp16(s4[j]); bi[j] = dec_fp16(b4[j]); }
    }

    f32x4 v;
    #pragma unroll
    for (int j = 0; j < 4; ++j) v[j] = s[j] * sc[j] + bi[j];

    if (xf == F_FP32) {
        *(f32x4*)((float*)yv + base) = v;
    } else if (xf == F_BF16) {
        u16x4 o;
        #pragma unroll
        for (int j = 0; j < 4; ++j) o[j] = enc_bf16_rne(v[j]);
        *(u16x4*)((unsigned short*)yv + base) = o;
    } else {
        u16x4 o;
        #pragma unroll
        for (int j = 0; j < 4; ++j) {
            __half h = __float2half(v[j]);
            o[j] = *(unsigned short*)&h;
        }
        *(u16x4*)((unsigned short*)yv + base) = o;
    }
}

extern "C" void kernel_launch(void* const* d_in, const int* in_sizes, int n_in,
                              void* d_out, int out_size, void* d_ws, size_t ws_size,
                              hipStream_t stream) {
    unsigned short* xbf = (unsigned short*)d_ws;                    // 512 KB
    float*          pws = (float*)((char*)d_ws + (1 << 20));        // 32 MB partials

    prep_x<<<64, 256, 0, stream>>>(d_in[0], xbf);
    w8a16_main<<<(OUT_F / CHW) * KSPLIT / 4, BLOCK, 0, stream>>>(
        (const int*)d_in[1], xbf, pws);
    reduce_k<<<(TOKENS * OUT_F / 4) / 256, 256, 0, stream>>>(
        pws, d_in[0], d_in[2], d_in[3], d_out);
}